// Round 1
// baseline (475.484 us; speedup 1.0000x reference)
//
#include <hip/hip_runtime.h>
#include <hip/hip_bf16.h>
#include <stdint.h>

#define B_N 8
#define T_N 2048
#define FDIM_N 512
#define H_N 8
#define DK_N 64

typedef float f32x4 __attribute__((ext_vector_type(4)));
typedef float float4v __attribute__((ext_vector_type(4)));
typedef __bf16 bf16x8 __attribute__((ext_vector_type(8)));
typedef unsigned short ushort4v __attribute__((ext_vector_type(4)));
typedef unsigned short ushort8v __attribute__((ext_vector_type(8)));

static __device__ __forceinline__ unsigned short f2bf(float f) {
  unsigned int u = __builtin_bit_cast(unsigned int, f);
  u += 0x7fffu + ((u >> 16) & 1u);
  return (unsigned short)(u >> 16);
}

static __device__ __forceinline__ void gld_lds16(const void* g, void* l) {
  __builtin_amdgcn_global_load_lds(
      (const __attribute__((address_space(1))) unsigned int*)g,
      (__attribute__((address_space(3))) unsigned int*)l, 16, 0, 0);
}

static __device__ __forceinline__ bf16x8 ld_bf8(const unsigned short* p) {
  return *reinterpret_cast<const bf16x8*>(p);
}

// ---------------- mask packing: int32 -> bitmask u64 ----------------
__global__ __launch_bounds__(256) void pack_mask_k(const int* __restrict__ m,
                                                   unsigned long long* __restrict__ o) {
  const size_t n = (size_t)B_N * T_N * T_N;
  const size_t stride = (size_t)2048 * 256;
  for (size_t i = (size_t)blockIdx.x * 256 + threadIdx.x; i < n; i += stride) {
    unsigned long long b = __ballot(m[i] != 0);
    if ((threadIdx.x & 63) == 0) o[i >> 6] = b;
  }
}

// ---------------- GEMM: C[m][n] = sum_k A[m][k] * W[n][k] + bias[n] ----------------
// M=16384, N=512, K=512. 128x128 tile, BK=32, 4 waves (2x2), 16x16x32 bf16 MFMA.
// OUTMODE 0: bf16 out at [((b*8+h)*2048+t)*64+d]   (q/k layout)
// OUTMODE 1: bf16 out at [((b*8+h)*64+d)*2048+t]   (V transposed)
// OUTMODE 2: f32 out at [m*512+n]                  (final output)
template <int OUTMODE, bool ABF16>
__global__ __launch_bounds__(256, 2) void gemm_bt_k(const void* __restrict__ Ap,
                                                    const float* __restrict__ Wp,
                                                    const float* __restrict__ biasp,
                                                    void* __restrict__ Cp) {
  __shared__ unsigned short As[128 * 32];
  __shared__ unsigned short Bs[128 * 32];
  const int tid = threadIdx.x;
  const int lane = tid & 63, w = tid >> 6;
  const int lr = lane & 15, lg = lane >> 4;
  const int nblk = gridDim.x;
  const int id = blockIdx.x;
  const int work = (id & 7) * (nblk >> 3) + (id >> 3);  // XCD swizzle (nblk % 8 == 0)
  const int m0 = (work >> 2) * 128, n0 = (work & 3) * 128;
  const int wm = (w & 1) * 64, wn = (w >> 1) * 64;
  const int row = tid >> 1, half = tid & 1;

  f32x4 acc[4][4];
  const f32x4 z4 = {0.f, 0.f, 0.f, 0.f};
#pragma unroll
  for (int i = 0; i < 4; ++i)
#pragma unroll
    for (int j = 0; j < 4; ++j) acc[i][j] = z4;

  for (int k0 = 0; k0 < 512; k0 += 32) {
    __syncthreads();
    // stage A tile (128 x 32)
    if constexpr (!ABF16) {
      const float* src = (const float*)Ap + (size_t)(m0 + row) * 512 + k0 + half * 16;
      unsigned short* dst = &As[row * 32 + half * 16];
#pragma unroll
      for (int i = 0; i < 4; ++i) {
        const float4v v = *reinterpret_cast<const float4v*>(src + i * 4);
        const ushort4v o = {f2bf(v.x), f2bf(v.y), f2bf(v.z), f2bf(v.w)};
        *reinterpret_cast<ushort4v*>(dst + i * 4) = o;
      }
    } else {
      const unsigned short* src =
          (const unsigned short*)Ap + (size_t)(m0 + row) * 512 + k0 + half * 16;
      unsigned short* dst = &As[row * 32 + half * 16];
#pragma unroll
      for (int i = 0; i < 2; ++i)
        *reinterpret_cast<ushort8v*>(dst + i * 8) =
            *reinterpret_cast<const ushort8v*>(src + i * 8);
    }
    // stage B tile = W rows (n) x k
    {
      const float* src = Wp + (size_t)(n0 + row) * 512 + k0 + half * 16;
      unsigned short* dst = &Bs[row * 32 + half * 16];
#pragma unroll
      for (int i = 0; i < 4; ++i) {
        const float4v v = *reinterpret_cast<const float4v*>(src + i * 4);
        const ushort4v o = {f2bf(v.x), f2bf(v.y), f2bf(v.z), f2bf(v.w)};
        *reinterpret_cast<ushort4v*>(dst + i * 4) = o;
      }
    }
    __syncthreads();
    bf16x8 af[4], bw[4];
#pragma unroll
    for (int mt = 0; mt < 4; ++mt) af[mt] = ld_bf8(&As[(wm + mt * 16 + lr) * 32 + lg * 8]);
#pragma unroll
    for (int nt = 0; nt < 4; ++nt) bw[nt] = ld_bf8(&Bs[(wn + nt * 16 + lr) * 32 + lg * 8]);
#pragma unroll
    for (int mt = 0; mt < 4; ++mt)
#pragma unroll
      for (int nt = 0; nt < 4; ++nt)
        acc[mt][nt] =
            __builtin_amdgcn_mfma_f32_16x16x32_bf16(af[mt], bw[nt], acc[mt][nt], 0, 0, 0);
  }

#pragma unroll
  for (int nt = 0; nt < 4; ++nt) {
    const int n = n0 + wn + nt * 16 + lr;
    const float bias = biasp[n];
#pragma unroll
    for (int mt = 0; mt < 4; ++mt) {
#pragma unroll
      for (int j = 0; j < 4; ++j) {
        const int m = m0 + wm + mt * 16 + lg * 4 + j;
        const float v = acc[mt][nt][j] + bias;
        if constexpr (OUTMODE == 0) {
          const int bb = m >> 11, t = m & 2047;
          const int hh = n >> 6, d = n & 63;
          ((unsigned short*)Cp)[(((size_t)(bb * 8 + hh) * 2048 + t) << 6) + d] = f2bf(v);
        } else if constexpr (OUTMODE == 1) {
          const int bb = m >> 11, t = m & 2047;
          const int hh = n >> 6, d = n & 63;
          ((unsigned short*)Cp)[(((size_t)(bb * 8 + hh) * 64 + d) << 11) + t] = f2bf(v);
        } else {
          ((float*)Cp)[(size_t)m * 512 + n] = v;
        }
      }
    }
  }
}

// ---------------- flash attention, QBLK=128 (4 waves x 32 rows), KVBLK=64 ----------------
__global__ __launch_bounds__(256, 2) void attn_k(
    const unsigned short* __restrict__ qg, const unsigned short* __restrict__ kg,
    const unsigned short* __restrict__ vtg, const unsigned long long* __restrict__ mb,
    unsigned short* __restrict__ xg) {
  __shared__ unsigned short Qs[128 * 64];
  __shared__ unsigned short Ks[64 * 64];
  __shared__ unsigned short Vts[64 * 64];
  __shared__ unsigned short Ps[4 * 32 * 64];
  __shared__ unsigned long long Msk[128];

  const int tid = threadIdx.x;
  const int lane = tid & 63, w = tid >> 6;
  const int lr = lane & 15, lg = lane >> 4;
  const int id = blockIdx.x;
  const int work = (id & 7) * 128 + (id >> 3);  // XCD swizzle: one bh per XCD chunk
  const int bh = work >> 4, qt0 = work & 15;
  const int b = bh >> 3, h = bh & 7;
  const int q0 = qt0 * 128;

  // stage Q tile once (128 x 64 bf16 = 16 KB)
  {
    const unsigned short* src = qg + ((size_t)bh * T_N + q0) * DK_N;
#pragma unroll
    for (int it = 0; it < 4; ++it) {
      const int c = it * 256 + tid;
      gld_lds16(src + (size_t)c * 8, &Qs[c * 8]);
    }
  }

  f32x4 O[2][4];
  float m_run[2][4], l_run[2][4];
  const f32x4 z4 = {0.f, 0.f, 0.f, 0.f};
#pragma unroll
  for (int qt = 0; qt < 2; ++qt) {
#pragma unroll
    for (int dt = 0; dt < 4; ++dt) O[qt][dt] = z4;
#pragma unroll
    for (int j = 0; j < 4; ++j) { m_run[qt][j] = -3.0e38f; l_run[qt][j] = 0.f; }
  }

  for (int kt = 0; kt < 32; ++kt) {
    __syncthreads();  // previous compute done (also drains Q staging on kt==0)
    {
      const unsigned short* src = kg + ((size_t)bh * T_N + kt * 64) * DK_N;
#pragma unroll
      for (int it = 0; it < 2; ++it) {
        const int c = it * 256 + tid;
        gld_lds16(src + (size_t)c * 8, &Ks[c * 8]);
      }
#pragma unroll
      for (int it = 0; it < 2; ++it) {
        const int c = it * 256 + tid;
        const int r = c >> 3, co = (c & 7) * 8;
        gld_lds16(vtg + ((size_t)bh * DK_N + r) * T_N + kt * 64 + co, &Vts[c * 8]);
      }
      if (tid < 128) Msk[tid] = mb[((size_t)b * T_N + q0 + tid) * (T_N / 64) + kt];
    }
    __syncthreads();

    // ---- S = Q K^T ----
    bf16x8 aq[2][2], bk[4][2];
#pragma unroll
    for (int qt = 0; qt < 2; ++qt)
#pragma unroll
      for (int kk = 0; kk < 2; ++kk)
        aq[qt][kk] = ld_bf8(&Qs[(w * 32 + qt * 16 + lr) * 64 + kk * 32 + lg * 8]);
#pragma unroll
    for (int st = 0; st < 4; ++st)
#pragma unroll
      for (int kk = 0; kk < 2; ++kk)
        bk[st][kk] = ld_bf8(&Ks[(st * 16 + lr) * 64 + kk * 32 + lg * 8]);

    f32x4 S[2][4];
#pragma unroll
    for (int qt = 0; qt < 2; ++qt)
#pragma unroll
      for (int st = 0; st < 4; ++st) {
        f32x4 acc = z4;
        acc = __builtin_amdgcn_mfma_f32_16x16x32_bf16(aq[qt][0], bk[st][0], acc, 0, 0, 0);
        acc = __builtin_amdgcn_mfma_f32_16x16x32_bf16(aq[qt][1], bk[st][1], acc, 0, 0, 0);
        S[qt][st] = acc;
      }

    // ---- masked online softmax (row = C-layout row = lg*4+j) ----
#pragma unroll
    for (int qt = 0; qt < 2; ++qt) {
#pragma unroll
      for (int j = 0; j < 4; ++j) {
        const unsigned long long mrow = Msk[w * 32 + qt * 16 + lg * 4 + j];
        float sv[4];
        float mx = -3.0e38f;
#pragma unroll
        for (int st = 0; st < 4; ++st) {
          float v = S[qt][st][j] * 0.125f;
          if ((mrow >> (st * 16 + lr)) & 1ull) v = -10000.f;
          sv[st] = v;
          mx = fmaxf(mx, v);
        }
        mx = fmaxf(mx, __shfl_xor(mx, 1));
        mx = fmaxf(mx, __shfl_xor(mx, 2));
        mx = fmaxf(mx, __shfl_xor(mx, 4));
        mx = fmaxf(mx, __shfl_xor(mx, 8));
        const float mnew = fmaxf(m_run[qt][j], mx);
        const float corr = __expf(m_run[qt][j] - mnew);
        m_run[qt][j] = mnew;
        float rs = 0.f;
#pragma unroll
        for (int st = 0; st < 4; ++st) {
          const float pv = (sv[st] < -9999.f) ? 0.f : __expf(sv[st] - mnew);
          rs += pv;
          Ps[w * 2048 + (qt * 16 + lg * 4 + j) * 64 + st * 16 + lr] = f2bf(pv);
        }
        rs += __shfl_xor(rs, 1);
        rs += __shfl_xor(rs, 2);
        rs += __shfl_xor(rs, 4);
        rs += __shfl_xor(rs, 8);
        l_run[qt][j] = l_run[qt][j] * corr + rs;
#pragma unroll
        for (int dt = 0; dt < 4; ++dt) O[qt][dt][j] *= corr;
      }
    }

    // ---- O += P V  (Vts stores V^T so B-frag is the bt-pattern read) ----
    bf16x8 vb[4][2];
#pragma unroll
    for (int dt = 0; dt < 4; ++dt)
#pragma unroll
      for (int sc = 0; sc < 2; ++sc)
        vb[dt][sc] = ld_bf8(&Vts[(dt * 16 + lr) * 64 + sc * 32 + lg * 8]);
#pragma unroll
    for (int qt = 0; qt < 2; ++qt) {
      bf16x8 pa[2];
#pragma unroll
      for (int sc = 0; sc < 2; ++sc)
        pa[sc] = ld_bf8(&Ps[w * 2048 + (qt * 16 + lr) * 64 + sc * 32 + lg * 8]);
#pragma unroll
      for (int dt = 0; dt < 4; ++dt) {
        O[qt][dt] = __builtin_amdgcn_mfma_f32_16x16x32_bf16(pa[0], vb[dt][0], O[qt][dt], 0, 0, 0);
        O[qt][dt] = __builtin_amdgcn_mfma_f32_16x16x32_bf16(pa[1], vb[dt][1], O[qt][dt], 0, 0, 0);
      }
    }
  }

  // ---- epilogue: x[b][t][h*64+d] = O / l  (bf16) ----
#pragma unroll
  for (int qt = 0; qt < 2; ++qt)
#pragma unroll
    for (int j = 0; j < 4; ++j) {
      const float l = l_run[qt][j];
      const float inv = (l > 0.f) ? 1.f / l : 0.f;
      const int q = q0 + w * 32 + qt * 16 + lg * 4 + j;
#pragma unroll
      for (int dt = 0; dt < 4; ++dt) {
        const int d = dt * 16 + lr;
        xg[((size_t)(b * T_N + q)) * FDIM_N + h * 64 + d] = f2bf(O[qt][dt][j] * inv);
      }
    }
}

extern "C" void kernel_launch(void* const* d_in, const int* in_sizes, int n_in,
                              void* d_out, int out_size, void* d_ws, size_t ws_size,
                              hipStream_t stream) {
  const float* query = (const float*)d_in[0];
  const float* key = (const float*)d_in[1];
  const float* value = (const float*)d_in[2];
  const int* mask = (const int*)d_in[3];
  const float* Wq = (const float*)d_in[4];
  const float* bq = (const float*)d_in[5];
  const float* Wk = (const float*)d_in[6];
  const float* bk = (const float*)d_in[7];
  const float* Wv = (const float*)d_in[8];
  const float* bv = (const float*)d_in[9];
  const float* Wo = (const float*)d_in[10];
  const float* bo = (const float*)d_in[11];

  const size_t NE = (size_t)16384 * 512;
  unsigned short* q_scr = (unsigned short*)d_ws;
  unsigned short* k_scr = q_scr + NE;
  unsigned short* vT_scr = k_scr + NE;
  unsigned short* x_scr = vT_scr + NE;
  unsigned long long* mbits = (unsigned long long*)(x_scr + NE);  // 4.19 MB

  pack_mask_k<<<2048, 256, 0, stream>>>(mask, mbits);
  gemm_bt_k<0, false><<<512, 256, 0, stream>>>(query, Wq, bq, q_scr);
  gemm_bt_k<0, false><<<512, 256, 0, stream>>>(key, Wk, bk, k_scr);
  gemm_bt_k<1, false><<<512, 256, 0, stream>>>(value, Wv, bv, vT_scr);
  attn_k<<<1024, 256, 0, stream>>>(q_scr, k_scr, vT_scr, mbits, x_scr);
  gemm_bt_k<2, true><<<512, 256, 0, stream>>>(x_scr, Wo, bo, (float*)d_out);
}

// Round 2
// 446.553 us; speedup vs baseline: 1.0648x; 1.0648x over previous
//
#include <hip/hip_runtime.h>
#include <hip/hip_bf16.h>
#include <stdint.h>

#define B_N 8
#define T_N 2048
#define FDIM_N 512
#define H_N 8
#define DK_N 64

typedef float f32x4 __attribute__((ext_vector_type(4)));
typedef float float4v __attribute__((ext_vector_type(4)));
typedef __bf16 bf16x8 __attribute__((ext_vector_type(8)));
typedef unsigned short ushort4v __attribute__((ext_vector_type(4)));
typedef unsigned short ushort8v __attribute__((ext_vector_type(8)));

#if __has_builtin(__builtin_amdgcn_exp2f)
#define EXP2F(x) __builtin_amdgcn_exp2f(x)
#else
#define EXP2F(x) exp2f(x)
#endif

static __device__ __forceinline__ unsigned short f2bf(float f) {
  unsigned int u = __builtin_bit_cast(unsigned int, f);
  u += 0x7fffu + ((u >> 16) & 1u);
  return (unsigned short)(u >> 16);
}

static __device__ __forceinline__ void gld_lds16(const void* g, void* l) {
  __builtin_amdgcn_global_load_lds(
      (const __attribute__((address_space(1))) unsigned int*)g,
      (__attribute__((address_space(3))) unsigned int*)l, 16, 0, 0);
}

static __device__ __forceinline__ bf16x8 ld_bf8(const unsigned short* p) {
  return *reinterpret_cast<const bf16x8*>(p);
}

// elem-offset XOR swizzle for 64-elem bf16 rows (8-elem granules, spreads 8 rows
// over the full 128B row so stride-128B fragment reads hit all 32 banks)
#define SWZ8(row, colE) ((colE) ^ (((row) & 7) << 3))

// ---------------- mask packing: int32 -> bitmask u64 ----------------
__global__ __launch_bounds__(256) void pack_mask_k(const int* __restrict__ m,
                                                   unsigned long long* __restrict__ o) {
  const size_t n = (size_t)B_N * T_N * T_N;
  const size_t stride = (size_t)2048 * 256;
  for (size_t i = (size_t)blockIdx.x * 256 + threadIdx.x; i < n; i += stride) {
    unsigned long long b = __ballot(m[i] != 0);
    if ((threadIdx.x & 63) == 0) o[i >> 6] = b;
  }
}

// ---------------- f32 -> bf16 conversion (streaming) ----------------
__global__ __launch_bounds__(256) void cvt_bf16_k(const float* __restrict__ in,
                                                  unsigned short* __restrict__ out, int n8) {
  const int stride = gridDim.x * 256;
  for (int i = blockIdx.x * 256 + threadIdx.x; i < n8; i += stride) {
    const float4v a = *reinterpret_cast<const float4v*>(in + (size_t)i * 8);
    const float4v b = *reinterpret_cast<const float4v*>(in + (size_t)i * 8 + 4);
    const ushort8v o = {f2bf(a.x), f2bf(a.y), f2bf(a.z), f2bf(a.w),
                        f2bf(b.x), f2bf(b.y), f2bf(b.z), f2bf(b.w)};
    *reinterpret_cast<ushort8v*>(out + (size_t)i * 8) = o;
  }
}

__global__ __launch_bounds__(256) void cvt_w4_k(const float* __restrict__ w0,
                                                const float* __restrict__ w1,
                                                const float* __restrict__ w2,
                                                const float* __restrict__ w3,
                                                unsigned short* __restrict__ out) {
  const int i = blockIdx.x * 256 + threadIdx.x;  // 131072 threads = 4 * 32768 chunks
  const int wsel = i >> 15, idx = i & 32767;
  const float* w = (wsel == 0) ? w0 : (wsel == 1) ? w1 : (wsel == 2) ? w2 : w3;
  const float4v a = *reinterpret_cast<const float4v*>(w + (size_t)idx * 8);
  const float4v b = *reinterpret_cast<const float4v*>(w + (size_t)idx * 8 + 4);
  const ushort8v o = {f2bf(a.x), f2bf(a.y), f2bf(a.z), f2bf(a.w),
                      f2bf(b.x), f2bf(b.y), f2bf(b.z), f2bf(b.w)};
  *reinterpret_cast<ushort8v*>(out + (size_t)i * 8) = o;
}

// ---------------- GEMM: C[m][n] = sum_k A[m][k] * W[n][k] + bias[n] ----------------
// All-bf16 inputs, m97 pattern: global_load_lds w=16, BK=64, swizzled LDS.
// M=16384, N=512, K=512. 128x128 tile, 4 waves (2x2), 16x16x32 bf16 MFMA.
// OUTMODE 0: bf16 out at [((b*8+h)*2048+t)*64+d]   (q/k layout; SCALEQ -> *0.125)
// OUTMODE 1: bf16 out at [((b*8+h)*64+d)*2048+t]   (V transposed)
// OUTMODE 2: f32 out at [m*512+n]                  (final output)
template <int OUTMODE, bool SCALEQ>
__global__ __launch_bounds__(256, 3) void gemm_bt_k(const unsigned short* __restrict__ Ap,
                                                    const unsigned short* __restrict__ Wp,
                                                    const float* __restrict__ biasp,
                                                    void* __restrict__ Cp) {
  __shared__ unsigned short As[128 * 64];
  __shared__ unsigned short Bs[128 * 64];
  const int tid = threadIdx.x;
  const int lane = tid & 63, w = tid >> 6;
  const int lr = lane & 15, lg = lane >> 4;
  const int nblk = gridDim.x;
  const int id = blockIdx.x;
  const int work = (id & 7) * (nblk >> 3) + (id >> 3);  // XCD swizzle (nblk % 8 == 0)
  const int m0 = (work >> 2) * 128, n0 = (work & 3) * 128;
  const int wm = (w & 1) * 64, wn = (w >> 1) * 64;
  const int swz_rd = (lr & 7) << 3;

  f32x4 acc[4][4];
  const f32x4 z4 = {0.f, 0.f, 0.f, 0.f};
#pragma unroll
  for (int i = 0; i < 4; ++i)
#pragma unroll
    for (int j = 0; j < 4; ++j) acc[i][j] = z4;

  for (int k0 = 0; k0 < 512; k0 += 64) {
    __syncthreads();
#pragma unroll
    for (int i = 0; i < 4; ++i) {
      const int c = i * 256 + tid;
      const int row = c >> 3, ch = c & 7;
      const int sw = SWZ8(row, ch * 8);
      gld_lds16(Ap + (size_t)(m0 + row) * 512 + k0 + sw, &As[c * 8]);
      gld_lds16(Wp + (size_t)(n0 + row) * 512 + k0 + sw, &Bs[c * 8]);
    }
    __syncthreads();
    bf16x8 af[4][2], bw[4][2];
#pragma unroll
    for (int mt = 0; mt < 4; ++mt)
#pragma unroll
      for (int kk = 0; kk < 2; ++kk)
        af[mt][kk] = ld_bf8(&As[(wm + mt * 16 + lr) * 64 + ((kk * 32 + lg * 8) ^ swz_rd)]);
#pragma unroll
    for (int nt = 0; nt < 4; ++nt)
#pragma unroll
      for (int kk = 0; kk < 2; ++kk)
        bw[nt][kk] = ld_bf8(&Bs[(wn + nt * 16 + lr) * 64 + ((kk * 32 + lg * 8) ^ swz_rd)]);
#pragma unroll
    for (int kk = 0; kk < 2; ++kk)
#pragma unroll
      for (int mt = 0; mt < 4; ++mt)
#pragma unroll
        for (int nt = 0; nt < 4; ++nt)
          acc[mt][nt] =
              __builtin_amdgcn_mfma_f32_16x16x32_bf16(af[mt][kk], bw[nt][kk], acc[mt][nt], 0, 0, 0);
  }

#pragma unroll
  for (int nt = 0; nt < 4; ++nt) {
    const int n = n0 + wn + nt * 16 + lr;
    const float bias = biasp[n];
#pragma unroll
    for (int mt = 0; mt < 4; ++mt) {
#pragma unroll
      for (int j = 0; j < 4; ++j) {
        const int m = m0 + wm + mt * 16 + lg * 4 + j;
        float v = acc[mt][nt][j] + bias;
        if constexpr (SCALEQ) v *= 0.125f;  // fold 1/sqrt(dk) into q
        if constexpr (OUTMODE == 0) {
          const int bb = m >> 11, t = m & 2047;
          const int hh = n >> 6, d = n & 63;
          ((unsigned short*)Cp)[(((size_t)(bb * 8 + hh) * 2048 + t) << 6) + d] = f2bf(v);
        } else if constexpr (OUTMODE == 1) {
          const int bb = m >> 11, t = m & 2047;
          const int hh = n >> 6, d = n & 63;
          ((unsigned short*)Cp)[(((size_t)(bb * 8 + hh) * 64 + d) << 11) + t] = f2bf(v);
        } else {
          ((float*)Cp)[(size_t)m * 512 + n] = v;
        }
      }
    }
  }
}

// ---------------- flash attention ----------------
// QBLK=128 (4 waves x 32 rows), KVBLK=64, Q hoisted to registers,
// double-buffered K/V/mask staging, swizzled LDS, exp2-domain softmax.
__global__ __launch_bounds__(256, 3) void attn_k(
    const unsigned short* __restrict__ qg, const unsigned short* __restrict__ kg,
    const unsigned short* __restrict__ vtg, const unsigned long long* __restrict__ mb,
    unsigned short* __restrict__ xg) {
  __shared__ unsigned short Ks[2][64 * 64];
  __shared__ unsigned short Vts[2][64 * 64];
  __shared__ unsigned short Ps[4][32 * 64];
  __shared__ unsigned long long Msk[2][128];

  const int tid = threadIdx.x;
  const int lane = tid & 63, w = tid >> 6;
  const int lr = lane & 15, lg = lane >> 4;
  const int swz_rd = (lr & 7) << 3;
  const int id = blockIdx.x;
  const int work = (id & 7) * 128 + (id >> 3);  // XCD swizzle: one bh per XCD chunk
  const int bh = work >> 4, qt0 = work & 15;
  const int b = bh >> 3, h = bh & 7;
  const int q0 = qt0 * 128;

  // ---- Q fragments: loop-invariant, straight from global to registers ----
  bf16x8 aq[2][2];
#pragma unroll
  for (int qt = 0; qt < 2; ++qt)
#pragma unroll
    for (int kk = 0; kk < 2; ++kk)
      aq[qt][kk] =
          ld_bf8(qg + ((size_t)bh * T_N + q0 + w * 32 + qt * 16 + lr) * DK_N + kk * 32 + lg * 8);

  // ---- staging helper: K/V with pre-swizzled global source (LDS dest linear) ----
  auto STAGE = [&](int pb, int kt) {
#pragma unroll
    for (int it = 0; it < 2; ++it) {
      const int c = it * 256 + tid;
      const int row = c >> 3, ch = c & 7;
      const int sw = SWZ8(row, ch * 8);
      gld_lds16(kg + ((size_t)bh * T_N + kt * 64 + row) * DK_N + sw, &Ks[pb][c * 8]);
    }
#pragma unroll
    for (int it = 0; it < 2; ++it) {
      const int c = it * 256 + tid;
      const int row = c >> 3, ch = c & 7;
      const int sw = SWZ8(row, ch * 8);
      gld_lds16(vtg + ((size_t)bh * DK_N + row) * T_N + kt * 64 + sw, &Vts[pb][c * 8]);
    }
    if (tid < 128) Msk[pb][tid] = mb[((size_t)b * T_N + q0 + tid) * (T_N / 64) + kt];
  };

  f32x4 O[2][4];
  float m_run[2][4], l_run[2][4];
  const f32x4 z4 = {0.f, 0.f, 0.f, 0.f};
#pragma unroll
  for (int qt = 0; qt < 2; ++qt) {
#pragma unroll
    for (int dt = 0; dt < 4; ++dt) O[qt][dt] = z4;
#pragma unroll
    for (int j = 0; j < 4; ++j) { m_run[qt][j] = -3.0e38f; l_run[qt][j] = 0.f; }
  }

  STAGE(0, 0);
  __syncthreads();

  int cur = 0;
  for (int kt = 0; kt < 32; ++kt) {
    if (kt < 31) STAGE(cur ^ 1, kt + 1);  // overlaps with this tile's compute

    // ---- S = Q K^T (swizzled ds_read_b128, conflict-free) ----
    bf16x8 bk[4][2];
#pragma unroll
    for (int st = 0; st < 4; ++st)
#pragma unroll
      for (int kk = 0; kk < 2; ++kk)
        bk[st][kk] = ld_bf8(&Ks[cur][(st * 16 + lr) * 64 + ((kk * 32 + lg * 8) ^ swz_rd)]);

    f32x4 S[2][4];
#pragma unroll
    for (int qt = 0; qt < 2; ++qt)
#pragma unroll
      for (int st = 0; st < 4; ++st) {
        f32x4 acc = z4;
        acc = __builtin_amdgcn_mfma_f32_16x16x32_bf16(aq[qt][0], bk[st][0], acc, 0, 0, 0);
        acc = __builtin_amdgcn_mfma_f32_16x16x32_bf16(aq[qt][1], bk[st][1], acc, 0, 0, 0);
        S[qt][st] = acc;
      }

    // ---- masked online softmax, exp2 domain (q pre-scaled by 0.125) ----
#pragma unroll
    for (int qt = 0; qt < 2; ++qt) {
#pragma unroll
      for (int j = 0; j < 4; ++j) {
        const int prow = qt * 16 + lg * 4 + j;
        const unsigned long long mrow = Msk[cur][w * 32 + prow];
        float sv[4];
#pragma unroll
        for (int st = 0; st < 4; ++st) {
          const bool ms = (mrow >> (st * 16 + lr)) & 1ull;
          const float v = S[qt][st][j] * 1.44269504f;  // to log2 units
          sv[st] = ms ? -2.0e30f : v;
        }
        float mx = fmaxf(fmaxf(sv[0], sv[1]), fmaxf(sv[2], sv[3]));
        mx = fmaxf(mx, __shfl_xor(mx, 1));
        mx = fmaxf(mx, __shfl_xor(mx, 2));
        mx = fmaxf(mx, __shfl_xor(mx, 4));
        mx = fmaxf(mx, __shfl_xor(mx, 8));
        const float mnew = fmaxf(m_run[qt][j], mx);
        const float corr = EXP2F(m_run[qt][j] - mnew);
        m_run[qt][j] = mnew;
        float rs = 0.f;
#pragma unroll
        for (int st = 0; st < 4; ++st) {
          float pv = EXP2F(sv[st] - mnew);
          pv = (sv[st] == -2.0e30f) ? 0.f : pv;  // masked prob -> exactly 0
          rs += pv;
          Ps[w][prow * 64 + SWZ8(prow, 0) + (((st * 16 + lr)) ^ ((prow & 7) << 3)) - SWZ8(prow, 0)] =
              f2bf(pv);
        }
        rs += __shfl_xor(rs, 1);
        rs += __shfl_xor(rs, 2);
        rs += __shfl_xor(rs, 4);
        rs += __shfl_xor(rs, 8);
        l_run[qt][j] = l_run[qt][j] * corr + rs;
#pragma unroll
        for (int dt = 0; dt < 4; ++dt) O[qt][dt][j] *= corr;
      }
    }

    // ---- O += P V  (Vts stores V^T; Ps round-trip is wave-private, no barrier) ----
    bf16x8 vb[4][2];
#pragma unroll
    for (int dt = 0; dt < 4; ++dt)
#pragma unroll
      for (int sc = 0; sc < 2; ++sc)
        vb[dt][sc] = ld_bf8(&Vts[cur][(dt * 16 + lr) * 64 + ((sc * 32 + lg * 8) ^ swz_rd)]);
#pragma unroll
    for (int qt = 0; qt < 2; ++qt) {
      bf16x8 pa[2];
#pragma unroll
      for (int sc = 0; sc < 2; ++sc)
        pa[sc] = ld_bf8(&Ps[w][(qt * 16 + lr) * 64 + ((sc * 32 + lg * 8) ^ swz_rd)]);
#pragma unroll
      for (int dt = 0; dt < 4; ++dt) {
        O[qt][dt] = __builtin_amdgcn_mfma_f32_16x16x32_bf16(pa[0], vb[dt][0], O[qt][dt], 0, 0, 0);
        O[qt][dt] = __builtin_amdgcn_mfma_f32_16x16x32_bf16(pa[1], vb[dt][1], O[qt][dt], 0, 0, 0);
      }
    }

    __syncthreads();  // drains next-tile staging (vmcnt) + protects buffer swap
    cur ^= 1;
  }

  // ---- epilogue: x[b][t][h*64+d] = O / l  (bf16) ----
#pragma unroll
  for (int qt = 0; qt < 2; ++qt)
#pragma unroll
    for (int j = 0; j < 4; ++j) {
      const float l = l_run[qt][j];
      const float inv = (l > 0.f) ? 1.f / l : 0.f;
      const int q = q0 + w * 32 + qt * 16 + lg * 4 + j;
#pragma unroll
      for (int dt = 0; dt < 4; ++dt) {
        const int d = dt * 16 + lr;
        xg[((size_t)(b * T_N + q)) * FDIM_N + h * 64 + d] = f2bf(O[qt][dt][j] * inv);
      }
    }
}

extern "C" void kernel_launch(void* const* d_in, const int* in_sizes, int n_in,
                              void* d_out, int out_size, void* d_ws, size_t ws_size,
                              hipStream_t stream) {
  const float* query = (const float*)d_in[0];
  const float* key = (const float*)d_in[1];
  const float* value = (const float*)d_in[2];
  const int* mask = (const int*)d_in[3];
  const float* Wq = (const float*)d_in[4];
  const float* bq = (const float*)d_in[5];
  const float* Wk = (const float*)d_in[6];
  const float* bk = (const float*)d_in[7];
  const float* Wv = (const float*)d_in[8];
  const float* bv = (const float*)d_in[9];
  const float* Wo = (const float*)d_in[10];
  const float* bo = (const float*)d_in[11];

  const size_t NE = (size_t)16384 * 512;   // 8.39M elems
  const size_t WE = (size_t)512 * 512;     // 0.26M elems
  unsigned short* qb_in = (unsigned short*)d_ws;     // converted inputs (bf16)
  unsigned short* kb_in = qb_in + NE;
  unsigned short* vb_in = kb_in + NE;
  unsigned short* wqb = vb_in + NE;                  // converted weights (4x)
  unsigned short* q_scr = wqb + 4 * WE;              // projected q/k/vT (bf16)
  unsigned short* k_scr = q_scr + NE;
  unsigned short* vT_scr = k_scr + NE;
  unsigned short* x_scr = qb_in;                     // alias: qb_in dead after q-proj
  unsigned long long* mbits = (unsigned long long*)(vT_scr + NE);  // 4.19 MB

  pack_mask_k<<<2048, 256, 0, stream>>>(mask, mbits);
  cvt_bf16_k<<<2048, 256, 0, stream>>>(query, qb_in, (int)(NE / 8));
  cvt_bf16_k<<<2048, 256, 0, stream>>>(key, kb_in, (int)(NE / 8));
  cvt_bf16_k<<<2048, 256, 0, stream>>>(value, vb_in, (int)(NE / 8));
  cvt_w4_k<<<512, 256, 0, stream>>>(Wq, Wk, Wv, Wo, wqb);

  gemm_bt_k<0, true><<<512, 256, 0, stream>>>(qb_in, wqb + 0 * WE, bq, q_scr);
  gemm_bt_k<0, false><<<512, 256, 0, stream>>>(kb_in, wqb + 1 * WE, bk, k_scr);
  gemm_bt_k<1, false><<<512, 256, 0, stream>>>(vb_in, wqb + 2 * WE, bv, vT_scr);
  attn_k<<<1024, 256, 0, stream>>>(q_scr, k_scr, vT_scr, mbits, x_scr);
  gemm_bt_k<2, false><<<512, 256, 0, stream>>>(x_scr, wqb + 3 * WE, bo, (float*)d_out);
}

// Round 3
// 267.769 us; speedup vs baseline: 1.7757x; 1.6677x over previous
//
#include <hip/hip_runtime.h>
#include <hip/hip_bf16.h>
#include <stdint.h>

#define B_N 8
#define T_N 2048
#define FDIM_N 512
#define H_N 8
#define DK_N 64

typedef float f32x4 __attribute__((ext_vector_type(4)));
typedef float float4v __attribute__((ext_vector_type(4)));
typedef __bf16 bf16x8 __attribute__((ext_vector_type(8)));
typedef unsigned short ushort4v __attribute__((ext_vector_type(4)));
typedef unsigned short ushort8v __attribute__((ext_vector_type(8)));
typedef unsigned int uint2v __attribute__((ext_vector_type(2)));
typedef unsigned int uint4v __attribute__((ext_vector_type(4)));

#if __has_builtin(__builtin_amdgcn_exp2f)
#define EXP2F(x) __builtin_amdgcn_exp2f(x)
#else
#define EXP2F(x) exp2f(x)
#endif

static __device__ __forceinline__ unsigned short f2bf(float f) {
  unsigned int u = __builtin_bit_cast(unsigned int, f);
  u += 0x7fffu + ((u >> 16) & 1u);
  return (unsigned short)(u >> 16);
}

// v_cvt_pk_bf16_f32: lo -> bits[15:0], hi -> bits[31:16] (RNE)
static __device__ __forceinline__ unsigned cvtpk(float lo, float hi) {
  unsigned r;
  asm("v_cvt_pk_bf16_f32 %0, %1, %2" : "=v"(r) : "v"(lo), "v"(hi));
  return r;
}

static __device__ __forceinline__ void gld_lds16(const void* g, void* l) {
  __builtin_amdgcn_global_load_lds(
      (const __attribute__((address_space(1))) unsigned int*)g,
      (__attribute__((address_space(3))) unsigned int*)l, 16, 0, 0);
}

static __device__ __forceinline__ bf16x8 ld_bf8(const unsigned short* p) {
  return *reinterpret_cast<const bf16x8*>(p);
}

// elem-offset XOR swizzle for 64-elem bf16 rows (8-elem granules)
#define SWZ8(row, colE) ((colE) ^ (((row) & 7) << 3))

// combined softmax scale: 1/sqrt(64) * log2(e)  (exp2-domain softmax)
#define QSCALE 0.1803368801111244f

// ---------------- mask packing: int32 -> bitmask u64 ----------------
__global__ __launch_bounds__(256) void pack_mask_k(const int* __restrict__ m,
                                                   unsigned long long* __restrict__ o) {
  const size_t n = (size_t)B_N * T_N * T_N;
  const size_t stride = (size_t)2048 * 256;
  for (size_t i = (size_t)blockIdx.x * 256 + threadIdx.x; i < n; i += stride) {
    unsigned long long b = __ballot(m[i] != 0);
    if ((threadIdx.x & 63) == 0) o[i >> 6] = b;
  }
}

// ---------------- f32 -> bf16 conversion (streaming) ----------------
__global__ __launch_bounds__(256) void cvt_bf16_k(const float* __restrict__ in,
                                                  unsigned short* __restrict__ out, int n8) {
  const int stride = gridDim.x * 256;
  for (int i = blockIdx.x * 256 + threadIdx.x; i < n8; i += stride) {
    const float4v a = *reinterpret_cast<const float4v*>(in + (size_t)i * 8);
    const float4v b = *reinterpret_cast<const float4v*>(in + (size_t)i * 8 + 4);
    const ushort8v o = {f2bf(a.x), f2bf(a.y), f2bf(a.z), f2bf(a.w),
                        f2bf(b.x), f2bf(b.y), f2bf(b.z), f2bf(b.w)};
    *reinterpret_cast<ushort8v*>(out + (size_t)i * 8) = o;
  }
}

__global__ __launch_bounds__(256) void cvt_w4_k(const float* __restrict__ w0,
                                                const float* __restrict__ w1,
                                                const float* __restrict__ w2,
                                                const float* __restrict__ w3,
                                                unsigned short* __restrict__ out) {
  const int i = blockIdx.x * 256 + threadIdx.x;
  const int wsel = i >> 15, idx = i & 32767;
  const float* w = (wsel == 0) ? w0 : (wsel == 1) ? w1 : (wsel == 2) ? w2 : w3;
  const float4v a = *reinterpret_cast<const float4v*>(w + (size_t)idx * 8);
  const float4v b = *reinterpret_cast<const float4v*>(w + (size_t)idx * 8 + 4);
  const ushort8v o = {f2bf(a.x), f2bf(a.y), f2bf(a.z), f2bf(a.w),
                      f2bf(b.x), f2bf(b.y), f2bf(b.z), f2bf(b.w)};
  *reinterpret_cast<ushort8v*>(out + (size_t)i * 8) = o;
}

// ---------------- GEMM: C[m][n] = sum_k A[m][k] * W[n][k] + bias[n] ----------------
// OUTMODE 0: bf16 out at [((b*8+h)*2048+t)*64+d]   (q/k layout; SCALEQ -> *QSCALE)
// OUTMODE 1: bf16 out at [((b*8+h)*64+d)*2048+pi(t)] (V^T with k-slot permutation pi
//            baked in: pi reorders t within each 32-block so attention's PV B-frag
//            k-slots line up with the swapped-QK^T softmax's lane-held k order)
// OUTMODE 2: f32 out at [m*512+n]                  (final output)
template <int OUTMODE, bool SCALEQ>
__global__ __launch_bounds__(256, 3) void gemm_bt_k(const unsigned short* __restrict__ Ap,
                                                    const unsigned short* __restrict__ Wp,
                                                    const float* __restrict__ biasp,
                                                    void* __restrict__ Cp) {
  __shared__ unsigned short As[128 * 64];
  __shared__ unsigned short Bs[128 * 64];
  const int tid = threadIdx.x;
  const int lane = tid & 63, w = tid >> 6;
  const int lr = lane & 15, lg = lane >> 4;
  const int nblk = gridDim.x;
  const int id = blockIdx.x;
  const int work = (id & 7) * (nblk >> 3) + (id >> 3);  // XCD swizzle
  const int m0 = (work >> 2) * 128, n0 = (work & 3) * 128;
  const int wm = (w & 1) * 64, wn = (w >> 1) * 64;
  const int swz_rd = (lr & 7) << 3;

  f32x4 acc[4][4];
  const f32x4 z4 = {0.f, 0.f, 0.f, 0.f};
#pragma unroll
  for (int i = 0; i < 4; ++i)
#pragma unroll
    for (int j = 0; j < 4; ++j) acc[i][j] = z4;

  for (int k0 = 0; k0 < 512; k0 += 64) {
    __syncthreads();
#pragma unroll
    for (int i = 0; i < 4; ++i) {
      const int c = i * 256 + tid;
      const int row = c >> 3, ch = c & 7;
      const int sw = SWZ8(row, ch * 8);
      gld_lds16(Ap + (size_t)(m0 + row) * 512 + k0 + sw, &As[c * 8]);
      gld_lds16(Wp + (size_t)(n0 + row) * 512 + k0 + sw, &Bs[c * 8]);
    }
    __syncthreads();
    bf16x8 af[4][2], bw[4][2];
#pragma unroll
    for (int mt = 0; mt < 4; ++mt)
#pragma unroll
      for (int kk = 0; kk < 2; ++kk)
        af[mt][kk] = ld_bf8(&As[(wm + mt * 16 + lr) * 64 + ((kk * 32 + lg * 8) ^ swz_rd)]);
#pragma unroll
    for (int nt = 0; nt < 4; ++nt)
#pragma unroll
      for (int kk = 0; kk < 2; ++kk)
        bw[nt][kk] = ld_bf8(&Bs[(wn + nt * 16 + lr) * 64 + ((kk * 32 + lg * 8) ^ swz_rd)]);
#pragma unroll
    for (int kk = 0; kk < 2; ++kk)
#pragma unroll
      for (int mt = 0; mt < 4; ++mt)
#pragma unroll
        for (int nt = 0; nt < 4; ++nt)
          acc[mt][nt] =
              __builtin_amdgcn_mfma_f32_16x16x32_bf16(af[mt][kk], bw[nt][kk], acc[mt][nt], 0, 0, 0);
  }

#pragma unroll
  for (int nt = 0; nt < 4; ++nt) {
    const int n = n0 + wn + nt * 16 + lr;
    const float bias = biasp[n];
#pragma unroll
    for (int mt = 0; mt < 4; ++mt) {
#pragma unroll
      for (int j = 0; j < 4; ++j) {
        const int m = m0 + wm + mt * 16 + lg * 4 + j;
        float v = acc[mt][nt][j] + bias;
        if constexpr (SCALEQ) v *= QSCALE;
        if constexpr (OUTMODE == 0) {
          const int bb = m >> 11, t = m & 2047;
          const int hh = n >> 6, d = n & 63;
          ((unsigned short*)Cp)[(((size_t)(bb * 8 + hh) * 2048 + t) << 6) + d] = f2bf(v);
        } else if constexpr (OUTMODE == 1) {
          const int bb = m >> 11, t = m & 2047;
          const int hh = n >> 6, d = n & 63;
          // pi: bits {0,1}->{0,1}, {2,3}->{3,4}, {4}->{2} within each 32-block
          const int tp = (t & ~31) | (((t >> 2) & 3) << 3) | (((t >> 4) & 1) << 2) | (t & 3);
          ((unsigned short*)Cp)[(((size_t)(bb * 8 + hh) * 64 + d) << 11) + tp] = f2bf(v);
        } else {
          ((float*)Cp)[(size_t)m * 512 + n] = v;
        }
      }
    }
  }
}

// ---------------- flash attention, swapped-QK^T / lane-local softmax ----------------
// QBLK=128 (4 waves x 32 rows), KVBLK=64. S^T = mfma(K,Q): lane lr owns q-row
// qt*16+lr holding k = st*16+lg*4+j. O^T = mfma(V^T,P): same col=q ownership, so
// softmax, rescale, and P-handoff are lane-local (no LDS P round-trip, 2 shfl/reduce).
__global__ __launch_bounds__(256, 3) void attn_k(
    const unsigned short* __restrict__ qg, const unsigned short* __restrict__ kg,
    const unsigned short* __restrict__ vtg, const unsigned long long* __restrict__ mb,
    unsigned short* __restrict__ xg) {
  __shared__ unsigned short Ks[2][64 * 64];
  __shared__ unsigned short Vts[2][64 * 64];
  __shared__ unsigned long long Msk[2][128];

  const int tid = threadIdx.x;
  const int lane = tid & 63, w = tid >> 6;
  const int lr = lane & 15, lg = lane >> 4;
  const int swz_rd = (lr & 7) << 3;
  const int id = blockIdx.x;
  const int work = (id & 7) * 128 + (id >> 3);  // XCD swizzle: one bh per XCD chunk
  const int bh = work >> 4, qt0 = work & 15;
  const int b = bh >> 3, h = bh & 7;
  const int q0 = qt0 * 128;

  // Q B-frags (loop-invariant, global->reg): lane supplies Q[q=qt*16+lr][d]
  bf16x8 aq[2][2];
#pragma unroll
  for (int qt = 0; qt < 2; ++qt)
#pragma unroll
    for (int kk = 0; kk < 2; ++kk)
      aq[qt][kk] =
          ld_bf8(qg + ((size_t)bh * T_N + q0 + w * 32 + qt * 16 + lr) * DK_N + kk * 32 + lg * 8);

  auto STAGE = [&](int pb_, int kt) {
#pragma unroll
    for (int it = 0; it < 2; ++it) {
      const int c = it * 256 + tid;
      const int row = c >> 3, ch = c & 7;
      const int sw = SWZ8(row, ch * 8);
      gld_lds16(kg + ((size_t)bh * T_N + kt * 64 + row) * DK_N + sw, &Ks[pb_][c * 8]);
    }
#pragma unroll
    for (int it = 0; it < 2; ++it) {
      const int c = it * 256 + tid;
      const int row = c >> 3, ch = c & 7;
      const int sw = SWZ8(row, ch * 8);
      gld_lds16(vtg + ((size_t)bh * DK_N + row) * T_N + kt * 64 + sw, &Vts[pb_][c * 8]);
    }
    if (tid < 128) Msk[pb_][tid] = mb[((size_t)b * T_N + q0 + tid) * (T_N / 64) + kt];
  };

  f32x4 OT[2][4];  // [qt][dt]: row d = dt*16+lg*4+j, col q = lr
  float m_run[2] = {-1.0e30f, -1.0e30f};
  float l_run[2] = {0.f, 0.f};
  const f32x4 z4 = {0.f, 0.f, 0.f, 0.f};
#pragma unroll
  for (int qt = 0; qt < 2; ++qt)
#pragma unroll
    for (int dt = 0; dt < 4; ++dt) OT[qt][dt] = z4;

  STAGE(0, 0);
  __syncthreads();

  int cur = 0;
  for (int kt = 0; kt < 32; ++kt) {
    if (kt < 31) STAGE(cur ^ 1, kt + 1);  // overlaps with this tile's compute

    // ---- S^T = K Q^T : per (qt,st) lane holds S^T[k=st*16+lg*4+j][q=qt*16+lr] ----
    f32x4 ST[2][4];
#pragma unroll
    for (int st = 0; st < 4; ++st) {
      const bf16x8 b0 = ld_bf8(&Ks[cur][(st * 16 + lr) * 64 + ((lg * 8) ^ swz_rd)]);
      const bf16x8 b1 = ld_bf8(&Ks[cur][(st * 16 + lr) * 64 + ((32 + lg * 8) ^ swz_rd)]);
#pragma unroll
      for (int qt = 0; qt < 2; ++qt) {
        f32x4 acc = z4;
        acc = __builtin_amdgcn_mfma_f32_16x16x32_bf16(b0, aq[qt][0], acc, 0, 0, 0);
        acc = __builtin_amdgcn_mfma_f32_16x16x32_bf16(b1, aq[qt][1], acc, 0, 0, 0);
        ST[qt][st] = acc;
      }
    }

    // ---- lane-local masked online softmax (exp2 domain; scale pre-folded in q) ----
    bf16x8 pb[2][2];
#pragma unroll
    for (int qt = 0; qt < 2; ++qt) {
      const unsigned long long mrow = Msk[cur][w * 32 + qt * 16 + lr];
      float p[4][4];
      float mst[4];
#pragma unroll
      for (int st = 0; st < 4; ++st) {
        const unsigned nib = (unsigned)(mrow >> (st * 16 + lg * 4)) & 0xFu;
        const f32x4 s = ST[qt][st];
        p[st][0] = (nib & 1u) ? -1.0e30f : s[0];
        p[st][1] = (nib & 2u) ? -1.0e30f : s[1];
        p[st][2] = (nib & 4u) ? -1.0e30f : s[2];
        p[st][3] = (nib & 8u) ? -1.0e30f : s[3];
        mst[st] = fmaxf(fmaxf(p[st][0], p[st][1]), fmaxf(p[st][2], p[st][3]));
      }
      float mx = fmaxf(fmaxf(mst[0], mst[1]), fmaxf(mst[2], mst[3]));
      mx = fmaxf(mx, __shfl_xor(mx, 16));
      mx = fmaxf(mx, __shfl_xor(mx, 32));
      const float mnew = fmaxf(m_run[qt], mx);
      const float corr = EXP2F(m_run[qt] - mnew);
      m_run[qt] = mnew;
      float rs4[4];
#pragma unroll
      for (int st = 0; st < 4; ++st) {
        const unsigned nib = (unsigned)(mrow >> (st * 16 + lg * 4)) & 0xFu;
#pragma unroll
        for (int j = 0; j < 4; ++j) {
          float e = EXP2F(p[st][j] - mnew);
          e = ((nib >> j) & 1u) ? 0.f : e;  // masked prob -> exactly 0
          p[st][j] = e;
        }
        rs4[st] = (p[st][0] + p[st][1]) + (p[st][2] + p[st][3]);
      }
      float rs = (rs4[0] + rs4[1]) + (rs4[2] + rs4[3]);
      rs += __shfl_xor(rs, 16);
      rs += __shfl_xor(rs, 32);
      l_run[qt] = l_run[qt] * corr + rs;
#pragma unroll
      for (int dt = 0; dt < 4; ++dt) {
#pragma unroll
        for (int j = 0; j < 4; ++j) OT[qt][dt][j] *= corr;
      }
      // pack P -> bf16 B-frags in-register (k-slot order matches pi-permuted V^T)
      uint4v pk0, pk1;
      pk0.x = cvtpk(p[0][0], p[0][1]); pk0.y = cvtpk(p[0][2], p[0][3]);
      pk0.z = cvtpk(p[1][0], p[1][1]); pk0.w = cvtpk(p[1][2], p[1][3]);
      pk1.x = cvtpk(p[2][0], p[2][1]); pk1.y = cvtpk(p[2][2], p[2][3]);
      pk1.z = cvtpk(p[3][0], p[3][1]); pk1.w = cvtpk(p[3][2], p[3][3]);
      pb[qt][0] = __builtin_bit_cast(bf16x8, pk0);
      pb[qt][1] = __builtin_bit_cast(bf16x8, pk1);
    }

    // ---- O^T += V^T P^T ----
#pragma unroll
    for (int dt = 0; dt < 4; ++dt) {
      const bf16x8 v0 = ld_bf8(&Vts[cur][(dt * 16 + lr) * 64 + ((lg * 8) ^ swz_rd)]);
      const bf16x8 v1 = ld_bf8(&Vts[cur][(dt * 16 + lr) * 64 + ((32 + lg * 8) ^ swz_rd)]);
#pragma unroll
      for (int qt = 0; qt < 2; ++qt) {
        OT[qt][dt] = __builtin_amdgcn_mfma_f32_16x16x32_bf16(v0, pb[qt][0], OT[qt][dt], 0, 0, 0);
        OT[qt][dt] = __builtin_amdgcn_mfma_f32_16x16x32_bf16(v1, pb[qt][1], OT[qt][dt], 0, 0, 0);
      }
    }

    __syncthreads();  // drains next-tile staging + protects buffer swap
    cur ^= 1;
  }

  // ---- epilogue: x[b][q][h*64+d] = O^T[d][q] / l ----
#pragma unroll
  for (int qt = 0; qt < 2; ++qt) {
    const float l = l_run[qt];
    const float inv = (l > 0.f) ? 1.f / l : 0.f;
    const int q = q0 + w * 32 + qt * 16 + lr;
#pragma unroll
    for (int dt = 0; dt < 4; ++dt) {
      uint2v o;
      o.x = cvtpk(OT[qt][dt][0] * inv, OT[qt][dt][1] * inv);
      o.y = cvtpk(OT[qt][dt][2] * inv, OT[qt][dt][3] * inv);
      *reinterpret_cast<uint2v*>(xg + ((size_t)(b * T_N + q)) * FDIM_N + h * 64 + dt * 16 +
                                 lg * 4) = o;
    }
  }
}

extern "C" void kernel_launch(void* const* d_in, const int* in_sizes, int n_in,
                              void* d_out, int out_size, void* d_ws, size_t ws_size,
                              hipStream_t stream) {
  const float* query = (const float*)d_in[0];
  const float* key = (const float*)d_in[1];
  const float* value = (const float*)d_in[2];
  const int* mask = (const int*)d_in[3];
  const float* Wq = (const float*)d_in[4];
  const float* bq = (const float*)d_in[5];
  const float* Wk = (const float*)d_in[6];
  const float* bk = (const float*)d_in[7];
  const float* Wv = (const float*)d_in[8];
  const float* bv = (const float*)d_in[9];
  const float* Wo = (const float*)d_in[10];
  const float* bo = (const float*)d_in[11];

  const size_t NE = (size_t)16384 * 512;
  const size_t WE = (size_t)512 * 512;
  unsigned short* qb_in = (unsigned short*)d_ws;
  unsigned short* kb_in = qb_in + NE;
  unsigned short* vb_in = kb_in + NE;
  unsigned short* wqb = vb_in + NE;
  unsigned short* q_scr = wqb + 4 * WE;
  unsigned short* k_scr = q_scr + NE;
  unsigned short* vT_scr = k_scr + NE;
  unsigned short* x_scr = qb_in;  // alias: qb_in dead after q-proj
  unsigned long long* mbits = (unsigned long long*)(vT_scr + NE);

  pack_mask_k<<<2048, 256, 0, stream>>>(mask, mbits);
  cvt_bf16_k<<<2048, 256, 0, stream>>>(query, qb_in, (int)(NE / 8));
  cvt_bf16_k<<<2048, 256, 0, stream>>>(key, kb_in, (int)(NE / 8));
  cvt_bf16_k<<<2048, 256, 0, stream>>>(value, vb_in, (int)(NE / 8));
  cvt_w4_k<<<512, 256, 0, stream>>>(Wq, Wk, Wv, Wo, wqb);

  gemm_bt_k<0, true><<<512, 256, 0, stream>>>(qb_in, wqb + 0 * WE, bq, q_scr);
  gemm_bt_k<0, false><<<512, 256, 0, stream>>>(kb_in, wqb + 1 * WE, bk, k_scr);
  gemm_bt_k<1, false><<<512, 256, 0, stream>>>(vb_in, wqb + 2 * WE, bv, vT_scr);
  attn_k<<<1024, 256, 0, stream>>>(q_scr, k_scr, vT_scr, mbits, x_scr);
  gemm_bt_k<2, false><<<512, 256, 0, stream>>>(x_scr, wqb + 3 * WE, bo, (float*)d_out);
}